// Round 11
// baseline (118.050 us; speedup 1.0000x reference)
//
#include <hip/hip_runtime.h>
#include <stdint.h>

#define B_ 4
#define T_ 2048
#define C_ 1024
#define H_ 128
#define NEG_BIG -3.0e38f
#define NCH 12

typedef __attribute__((ext_vector_type(8))) short short8;
typedef __attribute__((ext_vector_type(4))) float f32x4;
typedef __attribute__((ext_vector_type(4))) unsigned short ushort4v;
typedef __attribute__((ext_vector_type(8))) unsigned short ushort8v;

// cheap bf16 cast: round-half-up, <=0.5 ULP (validated: absmax unchanged)
__device__ __forceinline__ unsigned short f2bf(float f) {
  union { float f; unsigned u; } cv; cv.f = f;
  return (unsigned short)((cv.u + 0x8000u) >> 16);
}

__device__ __forceinline__ float bf2f(unsigned short s) {
  union { unsigned u; float f; } cv; cv.u = ((unsigned)s) << 16;
  return cv.f;
}

// scale = C^-0.5 = 1/32; folded with log2(e) for exp2-domain softmax
#define CSCALE 0.045084220027780106f

// ---------------------------------------------------------------------------
// Kernel 1: fused weight-cast + x-cast + QKV projection (R9/R10 version,
// unchanged — frozen for single-variable discipline).
// 64M x 64N x 64K tiles, grid = 128 rb x 6 cb = 768 blocks -> 3 blocks/CU.
// ---------------------------------------------------------------------------
__global__ __launch_bounds__(256, 3) void qkv_proj(const float* __restrict__ x,
                                                   const float* __restrict__ Wq,
                                                   const float* __restrict__ Wk,
                                                   const float* __restrict__ Wv,
                                                   unsigned short* __restrict__ Qb,
                                                   unsigned short* __restrict__ Kb,
                                                   unsigned short* __restrict__ VT) {
  __shared__ unsigned short As[2][64 * 64];   // 8 KB each
  __shared__ unsigned short Bs[2][64 * 64];   // 8 KB each

  const int tid  = threadIdx.x;
  const int wave = tid >> 6, lane = tid & 63;
  const int quad = lane >> 4, l15 = lane & 15;
  const int rb = blockIdx.x & 127, cb = blockIdx.x >> 7;  // siblings same XCD
  const int gm0 = rb * 64, gn0 = cb * 64;
  const int wm = wave >> 1, wn = wave & 1;

  // B staging: thread -> (row bn = tid&63, k-chunk16 bkc = tid>>6)
  const int bn = tid & 63, bkc = tid >> 6;
  const float* Wsrc = (cb < 2) ? Wq : (cb < 4) ? Wk : Wv;
  const int bh = (gn0 & 127) + bn;            // column within Wsrc

  // A staging: thread -> (row = tid>>3 (+32q), chunk = tid&7)
  const int axr = tid >> 3, axc = tid & 7;    // 32 rows x 8 chunks
  const float* gAx = x + (size_t)(gm0 + axr) * C_ + axc * 8;

  // fragment read offsets (shorts)
  int aoff[2][2], boff[2][2];
#pragma unroll
  for (int mt = 0; mt < 2; ++mt) {
    const int r = wm * 32 + mt * 16 + l15;
#pragma unroll
    for (int ks = 0; ks < 2; ++ks)
      aoff[mt][ks] = r * 64 + (((ks * 4 + quad) ^ r) & 7) * 8;
  }
#pragma unroll
  for (int nt = 0; nt < 2; ++nt) {
    const int r = wn * 32 + nt * 16 + l15;
#pragma unroll
    for (int ks = 0; ks < 2; ++ks)
      boff[nt][ks] = r * 64 + ((((ks * 4 + quad)) ^ r ^ (r >> 3)) & 7) * 8;
  }

  f32x4 acc[2][2];
  const f32x4 zero4 = {0.f, 0.f, 0.f, 0.f};
#pragma unroll
  for (int mt = 0; mt < 2; ++mt)
#pragma unroll
    for (int nt = 0; nt < 2; ++nt) acc[mt][nt] = zero4;

#define LOAD_B(ko_)                                                                \
  _Pragma("unroll")                                                                \
  for (int kk = 0; kk < 16; ++kk)                                                  \
    bv[kk] = Wsrc[(size_t)((ko_) + bkc * 16 + kk) * 128 + bh];

#define WRITE_B(buf)                                                               \
  {                                                                                \
    short8 bw0, bw1;                                                               \
    _Pragma("unroll")                                                              \
    for (int e = 0; e < 8; ++e) {                                                  \
      bw0[e] = (short)f2bf(bv[e]);                                                 \
      bw1[e] = (short)f2bf(bv[8 + e]);                                             \
    }                                                                              \
    const int sx = bn ^ (bn >> 3);                                                 \
    *(short8*)(&Bs[buf][bn * 64 + (((bkc * 2) ^ sx) & 7) * 8]) = bw0;              \
    *(short8*)(&Bs[buf][bn * 64 + (((bkc * 2 + 1) ^ sx) & 7) * 8]) = bw1;          \
  }

#define LOAD_A(ko_)                                                                \
  _Pragma("unroll")                                                                \
  for (int q = 0; q < 2; ++q) {                                                    \
    av0[q] = *(const f32x4*)(gAx + (size_t)(q * 32) * C_ + (ko_));                 \
    av1[q] = *(const f32x4*)(gAx + (size_t)(q * 32) * C_ + (ko_) + 4);             \
  }

#define WRITE_A(buf)                                                               \
  _Pragma("unroll")                                                                \
  for (int q = 0; q < 2; ++q) {                                                    \
    const int row = axr + q * 32;                                                  \
    short8 aw;                                                                     \
    _Pragma("unroll")                                                              \
    for (int e = 0; e < 4; ++e) {                                                  \
      aw[e]     = (short)f2bf(av0[q][e]);                                          \
      aw[4 + e] = (short)f2bf(av1[q][e]);                                          \
    }                                                                              \
    *(short8*)(&As[buf][row * 64 + ((axc ^ row) & 7) * 8]) = aw;                   \
  }

  f32x4 av0[2], av1[2];
  float bv[16];
  LOAD_A(0);
  LOAD_B(0);
  WRITE_A(0);
  WRITE_B(0);

  for (int kb = 0; kb < 16; ++kb) {
    __syncthreads();               // buf[kb&1] staged; prior reads of other done
    const int cur = kb & 1, nxt = cur ^ 1;
    if (kb + 1 < 16) {             // issue next-tile loads right after barrier
      LOAD_A((kb + 1) * 64);
      LOAD_B((kb + 1) * 64);
    }
    const unsigned short* Ac = As[cur];
    const unsigned short* Bc = Bs[cur];
#pragma unroll
    for (int ks = 0; ks < 2; ++ks) {
      short8 b0 = *(const short8*)(Bc + boff[0][ks]);
      short8 b1 = *(const short8*)(Bc + boff[1][ks]);
#pragma unroll
      for (int mt = 0; mt < 2; ++mt) {
        short8 a = *(const short8*)(Ac + aoff[mt][ks]);
        acc[mt][0] = __builtin_amdgcn_mfma_f32_16x16x32_bf16(a, b0, acc[mt][0], 0, 0, 0);
        acc[mt][1] = __builtin_amdgcn_mfma_f32_16x16x32_bf16(a, b1, acc[mt][1], 0, 0, 0);
      }
    }
    if (kb + 1 < 16) {             // cvt + write next tile after MFMAs issued
      WRITE_A(nxt);
      WRITE_B(nxt);
    }
  }
#undef LOAD_B
#undef WRITE_B
#undef LOAD_A
#undef WRITE_A

  // epilogue: D[row=quad*4+r][col=l15] per 16x16 tile
#pragma unroll
  for (int mt = 0; mt < 2; ++mt) {
    const int row0 = gm0 + wm * 32 + mt * 16 + quad * 4;
#pragma unroll
    for (int nt = 0; nt < 2; ++nt) {
      const int colbase = gn0 + wn * 32 + nt * 16;
      const int col = colbase + l15;
      if (colbase < 128) {          // Q (pre-scaled)
#pragma unroll
        for (int r = 0; r < 4; ++r)
          Qb[(size_t)(row0 + r) * H_ + col] = f2bf(acc[mt][nt][r] * CSCALE);
      } else if (colbase < 256) {   // K
#pragma unroll
        for (int r = 0; r < 4; ++r)
          Kb[(size_t)(row0 + r) * H_ + (col - 128)] = f2bf(acc[mt][nt][r]);
      } else {                      // V, transposed
        const int h = col - 256;
        const int bidx = row0 >> 11;
        const int t0 = row0 & 2047;
        ushort4v pk;
        pk[0] = f2bf(acc[mt][nt][0]); pk[1] = f2bf(acc[mt][nt][1]);
        pk[2] = f2bf(acc[mt][nt][2]); pk[3] = f2bf(acc[mt][nt][3]);
        *(ushort4v*)(VT + (size_t)(bidx * H_ + h) * T_ + t0) = pk;
      }
    }
  }
}

// ---------------------------------------------------------------------------
// Kernel 2: flash attention stage 1.
// R11: mod-12 chunking — block (b, jp, ch in [0,12)) does rows j1=jp and
// j2=31-jp with tiles { t == ch (mod 12), t <= j }. Grid 768 -> TRUE
// 3 blocks/CU (R10 built the 41 KB LDS capability but kept grid 512 = 2/CU,
// so the lever was never pulled). Variable ntt (2-4, one ntt=1 corner)
// desynchronizes co-resident blocks, breaking the barrier phase-lock so one
// block's MFMA overlaps another's softmax. T14 reg-staged single-buffer K/V,
// T13 defer-max, T5 setprio, shfl-alpha unchanged.
// ---------------------------------------------------------------------------
__global__ __launch_bounds__(256, 3) void attn1(const unsigned short* __restrict__ Qb,
                                                const unsigned short* __restrict__ Kb,
                                                const unsigned short* __restrict__ VT,
                                                unsigned short* __restrict__ Opart,
                                                float* __restrict__ mpart,
                                                float* __restrict__ lpart) {
  __shared__ unsigned short Ks[64 * 128];      // 16 KB; 16-slot rows
  __shared__ unsigned short Vs[128 * 64];      // 16 KB; 8-slot rows
  __shared__ unsigned short Pls[4][16 * 72];   // 9 KB, per-wave P, pad 72

  const int bid = blockIdx.x;
  const int b  = bid & 3;
  const int jp = (bid >> 2) & 15;
  const int ch = bid >> 6;         // 0..11
  const int j1 = jp, j2 = 31 - jp;
  const int n1 = (ch <= j1) ? ((j1 - ch) / NCH + 1) : 0;   // tiles for row j1
  const int n2 = (ch <= j2) ? ((j2 - ch) / NCH + 1) : 0;   // tiles for row j2 (>=1)
  const int ntt = n1 + n2;                                 // 1..4

  const int tid  = threadIdx.x;
  const int wave = tid >> 6, lane = tid & 63;
  const int quad = lane >> 4, l15 = lane & 15;

  const unsigned short* Kb_b = Kb + (size_t)(b * T_) * H_;
  const unsigned short* VT_b = VT + (size_t)(b * H_) * T_;

  const int k_row4 = lane >> 4, k_slot = lane & 15;
  const int v_row8 = lane >> 3, v_slot = lane & 7;

  // register staging buffers (32 VGPRs)
  f32x4 kreg[4], vreg[4];

  // absolute kv tile index for loop position i_
#define TILE(i_) (((i_) < n1) ? (ch + (i_) * NCH) : (ch + ((i_) - n1) * NCH))

  // issue global->reg loads for tile at kv0_
#define LOAD_KV(kv0_)                                                              \
  {                                                                                \
    _Pragma("unroll")                                                              \
    for (int i_ = 0; i_ < 4; ++i_) {                                               \
      const int r = wave * 16 + i_ * 4 + k_row4;                                   \
      const int c2 = (k_slot & 8) | ((k_slot ^ r) & 7);                            \
      kreg[i_] = *(const f32x4*)(Kb_b + (size_t)((kv0_) + r) * H_ + c2 * 8);       \
    }                                                                              \
    _Pragma("unroll")                                                              \
    for (int i_ = 0; i_ < 4; ++i_) {                                               \
      const int h = wave * 32 + i_ * 8 + v_row8;                                   \
      vreg[i_] = *(const f32x4*)(VT_b + (size_t)h * T_ + (kv0_) + ((v_slot ^ h) & 7) * 8); \
    }                                                                              \
  }

  // write staged regs -> LDS
#define WRITE_KV()                                                                 \
  {                                                                                \
    _Pragma("unroll")                                                              \
    for (int i_ = 0; i_ < 4; ++i_) {                                               \
      const int r = wave * 16 + i_ * 4 + k_row4;                                   \
      *(f32x4*)(&Ks[r * 128 + k_slot * 8]) = kreg[i_];                             \
    }                                                                              \
    _Pragma("unroll")                                                              \
    for (int i_ = 0; i_ < 4; ++i_) {                                               \
      const int h = wave * 32 + i_ * 8 + v_row8;                                   \
      *(f32x4*)(&Vs[h * 64 + v_slot * 8]) = vreg[i_];                              \
    }                                                                              \
  }

  // partial epilogue: un-normalized O (bf16) + m, l for row jr_
#define EPI(jr_)                                                                   \
  {                                                                                \
    const int pid = (b * 32 + (jr_)) * NCH + ch;                                   \
    unsigned short* po = Opart + (size_t)(pid * 64 + wave * 16) * H_;              \
    _Pragma("unroll")                                                              \
    for (int nth = 0; nth < 8; ++nth)                                              \
      _Pragma("unroll")                                                            \
      for (int r = 0; r < 4; ++r)                                                  \
        po[(quad * 4 + r) * H_ + nth * 16 + l15] = f2bf(O[nth][r]);                \
    if (lane < 16) {                                                               \
      mpart[pid * 64 + wave * 16 + lane] = m_;                                     \
      lpart[pid * 64 + wave * 16 + lane] = l_;                                     \
    }                                                                              \
  }

  // Q fragments for current row block
  int jr_cur = n1 ? j1 : j2;
  short8 aq[4];
  {
    const unsigned short* qrow = Qb + (size_t)(b * T_ + jr_cur * 64 + wave * 16 + l15) * H_;
#pragma unroll
    for (int ks = 0; ks < 4; ++ks)
      aq[ks] = *(const short8*)(qrow + ks * 32 + quad * 8);
  }

  // prologue: stage tile 0, issue loads for tile 1 (if any)
  LOAD_KV(TILE(0) * 64);
  WRITE_KV();
  if (ntt > 1) LOAD_KV(TILE(1) * 64);
  __syncthreads();

  const f32x4 zero4 = {0.f, 0.f, 0.f, 0.f};
  f32x4 O[8];
#pragma unroll
  for (int nth = 0; nth < 8; ++nth) O[nth] = zero4;
  float m_ = NEG_BIG, l_ = 0.f;

  for (int i = 0; i < ntt; ++i) {
    if (n1 && i == n1) {
      // finalize row j1, reset state, switch Q to row j2
      EPI(j1);
      m_ = NEG_BIG; l_ = 0.f;
#pragma unroll
      for (int nth = 0; nth < 8; ++nth) O[nth] = zero4;
      jr_cur = j2;
      const unsigned short* qrow = Qb + (size_t)(b * T_ + j2 * 64 + wave * 16 + l15) * H_;
#pragma unroll
      for (int ks = 0; ks < 4; ++ks)
        aq[ks] = *(const short8*)(qrow + ks * 32 + quad * 8);
    }
    const int ti  = TILE(i);
    const int kv0 = ti * 64;

    // ---- S^T = K . Q^T
    f32x4 ST[4];
    ST[0] = zero4; ST[1] = zero4; ST[2] = zero4; ST[3] = zero4;
    __builtin_amdgcn_s_setprio(1);
#pragma unroll
    for (int ntl = 0; ntl < 4; ++ntl) {
      const int kvr = ntl * 16 + l15;
#pragma unroll
      for (int ks = 0; ks < 4; ++ks) {
        const int c = ks * 4 + quad;
        const int slot = (c & 8) | ((c ^ kvr) & 7);
        short8 kf = *(const short8*)(Ks + kvr * 128 + slot * 8);
        ST[ntl] = __builtin_amdgcn_mfma_f32_16x16x32_bf16(kf, aq[ks], ST[ntl], 0, 0, 0);
      }
    }
    __builtin_amdgcn_s_setprio(0);

    // ---- causal mask (diagonal tile only)
    if (ti == jr_cur) {
      const int ql = jr_cur * 64 + wave * 16 + l15;
#pragma unroll
      for (int ntl = 0; ntl < 4; ++ntl)
#pragma unroll
        for (int r = 0; r < 4; ++r) {
          const int kl = kv0 + ntl * 16 + quad * 4 + r;
          if (kl > ql) ST[ntl][r] = NEG_BIG;
        }
    }

    // ---- softmax (per lane q=l15), defer-max (T13)
    float pmax = ST[0][0];
#pragma unroll
    for (int ntl = 0; ntl < 4; ++ntl)
#pragma unroll
      for (int r = 0; r < 4; ++r) pmax = fmaxf(pmax, ST[ntl][r]);
    pmax = fmaxf(pmax, __shfl_xor(pmax, 16));
    pmax = fmaxf(pmax, __shfl_xor(pmax, 32));
    if (!__all(pmax <= m_ + 8.f)) {
      const float mn = fmaxf(m_, pmax);
      const float alpha = __builtin_amdgcn_exp2f(m_ - mn);
      m_ = mn;
      l_ *= alpha;
      float alr[4];
#pragma unroll
      for (int r = 0; r < 4; ++r) alr[r] = __shfl(alpha, quad * 4 + r);
#pragma unroll
      for (int nth = 0; nth < 8; ++nth)
#pragma unroll
        for (int r = 0; r < 4; ++r) O[nth][r] *= alr[r];
    }
    float s = 0.f;
#pragma unroll
    for (int ntl = 0; ntl < 4; ++ntl)
#pragma unroll
      for (int r = 0; r < 4; ++r) {
        const float p = __builtin_amdgcn_exp2f(ST[ntl][r] - m_);
        ST[ntl][r] = p;
        s += p;
      }
    s += __shfl_xor(s, 16);
    s += __shfl_xor(s, 32);
    l_ += s;

    // ---- P -> LDS ([q][kv] layout; per-wave region, no barrier)
#pragma unroll
    for (int ntl = 0; ntl < 4; ++ntl) {
      ushort4v pk;
      pk[0] = f2bf(ST[ntl][0]); pk[1] = f2bf(ST[ntl][1]);
      pk[2] = f2bf(ST[ntl][2]); pk[3] = f2bf(ST[ntl][3]);
      *(ushort4v*)(&Pls[wave][l15 * 72 + ntl * 16 + quad * 4]) = pk;
    }

    // ---- O += P . V
    short8 ap0 = *(const short8*)(&Pls[wave][l15 * 72 + quad * 8]);
    short8 ap1 = *(const short8*)(&Pls[wave][l15 * 72 + 32 + quad * 8]);
    __builtin_amdgcn_s_setprio(1);
#pragma unroll
    for (int nth = 0; nth < 8; ++nth) {
      const int h = nth * 16 + l15;
      short8 v0 = *(const short8*)(Vs + h * 64 + ((quad ^ h) & 7) * 8);
      short8 v1 = *(const short8*)(Vs + h * 64 + (((4 + quad) ^ h) & 7) * 8);
      O[nth] = __builtin_amdgcn_mfma_f32_16x16x32_bf16(ap0, v0, O[nth], 0, 0, 0);
      O[nth] = __builtin_amdgcn_mfma_f32_16x16x32_bf16(ap1, v1, O[nth], 0, 0, 0);
    }
    __builtin_amdgcn_s_setprio(0);

    // ---- rotate staging: write tile i+1, issue loads for tile i+2
    if (i + 1 < ntt) {
      __syncthreads();             // all waves done reading Ks/Vs (tile i)
      WRITE_KV();                  // stage tile i+1 (regs loaded earlier)
      if (i + 2 < ntt) LOAD_KV(TILE(i + 2) * 64);
      __syncthreads();             // tile i+1 visible
    }
  }
  EPI(j2);
#undef TILE
#undef LOAD_KV
#undef WRITE_KV
#undef EPI
}

// ---------------------------------------------------------------------------
// Kernel 3: stage-2 combine, 512 blocks: b(4) x j(32) x qi(4); each block
// 16 q-rows x 128 h. Row j has contributors ch in [0, min(j+1,12)).
// ---------------------------------------------------------------------------
__global__ __launch_bounds__(256) void attn2(const unsigned short* __restrict__ Opart,
                                             const float* __restrict__ mpart,
                                             const float* __restrict__ lpart,
                                             float* __restrict__ out) {
  const int b = blockIdx.x & 3;
  const int j = (blockIdx.x >> 2) & 31;
  const int qi = blockIdx.x >> 7;     // 0..3
  const int nch = min(j + 1, NCH);    // 1..12
  const int tid = threadIdx.x;
  const int q = (tid >> 4) + qi * 16; // 0..63
  const int h0 = (tid & 15) * 8;
  const int pbase = (b * 32 + j) * NCH;

  float m_fin = NEG_BIG;
  for (int ch = 0; ch < nch; ++ch)
    m_fin = fmaxf(m_fin, mpart[(pbase + ch) * 64 + q]);
  float lf = 0.f;
  float o[8];
#pragma unroll
  for (int c = 0; c < 8; ++c) o[c] = 0.f;
  for (int ch = 0; ch < nch; ++ch) {
    const int pid = pbase + ch;
    const float sc = __builtin_amdgcn_exp2f(mpart[pid * 64 + q] - m_fin);
    lf += sc * lpart[pid * 64 + q];
    ushort8v pv = *(const ushort8v*)(Opart + (size_t)(pid * 64 + q) * H_ + h0);
#pragma unroll
    for (int c = 0; c < 8; ++c) o[c] += sc * bf2f(pv[c]);
  }
  const float inv = 1.0f / lf;
  float* op = out + (size_t)(b * T_ + j * 64 + q) * H_ + h0;
  f32x4 v0 = {o[0] * inv, o[1] * inv, o[2] * inv, o[3] * inv};
  f32x4 v1 = {o[4] * inv, o[5] * inv, o[6] * inv, o[7] * inv};
  *(f32x4*)(op) = v0;
  *(f32x4*)(op + 4) = v1;
}

// ---------------------------------------------------------------------------
extern "C" void kernel_launch(void* const* d_in, const int* in_sizes, int n_in,
                              void* d_out, int out_size, void* d_ws, size_t ws_size,
                              hipStream_t stream) {
  const float* x  = (const float*)d_in[0];
  const float* Wq = (const float*)d_in[1];
  const float* Wk = (const float*)d_in[2];
  const float* Wv = (const float*)d_in[3];
  float* out = (float*)d_out;

  char* ws = (char*)d_ws;
  unsigned short* Qb  = (unsigned short*)(ws + 1048576);    // [1 MB, 3 MB)
  unsigned short* Kb  = (unsigned short*)(ws + 3145728);    // [3 MB, 5 MB)
  unsigned short* VT  = (unsigned short*)(ws + 5242880);    // [5 MB, 7 MB)
  unsigned short* Opart = (unsigned short*)(ws + 8388608);  // [8 MB, 32 MB): 1536 pids x 64q x 128h bf16
  float* mpart = (float*)(ws + 33554432);                   // [32 MB, +384 KB)
  float* lpart = (float*)(ws + 33947648);                   // [32.375 MB, +384 KB)

  qkv_proj<<<dim3(768), dim3(256), 0, stream>>>(x, Wq, Wk, Wv, Qb, Kb, VT);
  attn1<<<dim3(768), dim3(256), 0, stream>>>(Qb, Kb, VT, Opart, mpart, lpart);
  attn2<<<dim3(512), dim3(256), 0, stream>>>(Opart, mpart, lpart, out);
}

// Round 12
// 115.251 us; speedup vs baseline: 1.0243x; 1.0243x over previous
//
#include <hip/hip_runtime.h>
#include <stdint.h>

#define B_ 4
#define T_ 2048
#define C_ 1024
#define H_ 128
#define NEG_BIG -3.0e38f

typedef __attribute__((ext_vector_type(8))) short short8;
typedef __attribute__((ext_vector_type(4))) float f32x4;
typedef __attribute__((ext_vector_type(4))) unsigned short ushort4v;
typedef __attribute__((ext_vector_type(8))) unsigned short ushort8v;

// cheap bf16 cast: round-half-up, <=0.5 ULP (validated: absmax unchanged)
__device__ __forceinline__ unsigned short f2bf(float f) {
  union { float f; unsigned u; } cv; cv.f = f;
  return (unsigned short)((cv.u + 0x8000u) >> 16);
}

__device__ __forceinline__ float bf2f(unsigned short s) {
  union { unsigned u; float f; } cv; cv.u = ((unsigned)s) << 16;
  return cv.f;
}

// scale = C^-0.5 = 1/32; folded with log2(e) for exp2-domain softmax
#define CSCALE 0.045084220027780106f

// ---------------------------------------------------------------------------
// Kernel 1: fused weight-cast + x-cast + QKV projection (R9/R10, best-known).
// 64M x 64N x 64K tiles, grid = 128 rb x 6 cb = 768 blocks -> 3 blocks/CU.
// B staged directly from W fp32 (reg + in-register f2bf).
// ---------------------------------------------------------------------------
__global__ __launch_bounds__(256, 3) void qkv_proj(const float* __restrict__ x,
                                                   const float* __restrict__ Wq,
                                                   const float* __restrict__ Wk,
                                                   const float* __restrict__ Wv,
                                                   unsigned short* __restrict__ Qb,
                                                   unsigned short* __restrict__ Kb,
                                                   unsigned short* __restrict__ VT) {
  __shared__ unsigned short As[2][64 * 64];   // 8 KB each
  __shared__ unsigned short Bs[2][64 * 64];   // 8 KB each

  const int tid  = threadIdx.x;
  const int wave = tid >> 6, lane = tid & 63;
  const int quad = lane >> 4, l15 = lane & 15;
  const int rb = blockIdx.x & 127, cb = blockIdx.x >> 7;  // siblings same XCD
  const int gm0 = rb * 64, gn0 = cb * 64;
  const int wm = wave >> 1, wn = wave & 1;

  // B staging: thread -> (row bn = tid&63, k-chunk16 bkc = tid>>6)
  const int bn = tid & 63, bkc = tid >> 6;
  const float* Wsrc = (cb < 2) ? Wq : (cb < 4) ? Wk : Wv;
  const int bh = (gn0 & 127) + bn;            // column within Wsrc

  // A staging: thread -> (row = tid>>3 (+32q), chunk = tid&7)
  const int axr = tid >> 3, axc = tid & 7;    // 32 rows x 8 chunks
  const float* gAx = x + (size_t)(gm0 + axr) * C_ + axc * 8;

  // fragment read offsets (shorts)
  int aoff[2][2], boff[2][2];
#pragma unroll
  for (int mt = 0; mt < 2; ++mt) {
    const int r = wm * 32 + mt * 16 + l15;
#pragma unroll
    for (int ks = 0; ks < 2; ++ks)
      aoff[mt][ks] = r * 64 + (((ks * 4 + quad) ^ r) & 7) * 8;
  }
#pragma unroll
  for (int nt = 0; nt < 2; ++nt) {
    const int r = wn * 32 + nt * 16 + l15;
#pragma unroll
    for (int ks = 0; ks < 2; ++ks)
      boff[nt][ks] = r * 64 + ((((ks * 4 + quad)) ^ r ^ (r >> 3)) & 7) * 8;
  }

  f32x4 acc[2][2];
  const f32x4 zero4 = {0.f, 0.f, 0.f, 0.f};
#pragma unroll
  for (int mt = 0; mt < 2; ++mt)
#pragma unroll
    for (int nt = 0; nt < 2; ++nt) acc[mt][nt] = zero4;

#define LOAD_B(ko_)                                                                \
  _Pragma("unroll")                                                                \
  for (int kk = 0; kk < 16; ++kk)                                                  \
    bv[kk] = Wsrc[(size_t)((ko_) + bkc * 16 + kk) * 128 + bh];

#define WRITE_B(buf)                                                               \
  {                                                                                \
    short8 bw0, bw1;                                                               \
    _Pragma("unroll")                                                              \
    for (int e = 0; e < 8; ++e) {                                                  \
      bw0[e] = (short)f2bf(bv[e]);                                                 \
      bw1[e] = (short)f2bf(bv[8 + e]);                                             \
    }                                                                              \
    const int sx = bn ^ (bn >> 3);                                                 \
    *(short8*)(&Bs[buf][bn * 64 + (((bkc * 2) ^ sx) & 7) * 8]) = bw0;              \
    *(short8*)(&Bs[buf][bn * 64 + (((bkc * 2 + 1) ^ sx) & 7) * 8]) = bw1;          \
  }

#define LOAD_A(ko_)                                                                \
  _Pragma("unroll")                                                                \
  for (int q = 0; q < 2; ++q) {                                                    \
    av0[q] = *(const f32x4*)(gAx + (size_t)(q * 32) * C_ + (ko_));                 \
    av1[q] = *(const f32x4*)(gAx + (size_t)(q * 32) * C_ + (ko_) + 4);             \
  }

#define WRITE_A(buf)                                                               \
  _Pragma("unroll")                                                                \
  for (int q = 0; q < 2; ++q) {                                                    \
    const int row = axr + q * 32;                                                  \
    short8 aw;                                                                     \
    _Pragma("unroll")                                                              \
    for (int e = 0; e < 4; ++e) {                                                  \
      aw[e]     = (short)f2bf(av0[q][e]);                                          \
      aw[4 + e] = (short)f2bf(av1[q][e]);                                          \
    }                                                                              \
    *(short8*)(&As[buf][row * 64 + ((axc ^ row) & 7) * 8]) = aw;                   \
  }

  f32x4 av0[2], av1[2];
  float bv[16];
  LOAD_A(0);
  LOAD_B(0);
  WRITE_A(0);
  WRITE_B(0);

  for (int kb = 0; kb < 16; ++kb) {
    __syncthreads();               // buf[kb&1] staged; prior reads of other done
    const int cur = kb & 1, nxt = cur ^ 1;
    if (kb + 1 < 16) {             // issue next-tile loads right after barrier
      LOAD_A((kb + 1) * 64);
      LOAD_B((kb + 1) * 64);
    }
    const unsigned short* Ac = As[cur];
    const unsigned short* Bc = Bs[cur];
#pragma unroll
    for (int ks = 0; ks < 2; ++ks) {
      short8 b0 = *(const short8*)(Bc + boff[0][ks]);
      short8 b1 = *(const short8*)(Bc + boff[1][ks]);
#pragma unroll
      for (int mt = 0; mt < 2; ++mt) {
        short8 a = *(const short8*)(Ac + aoff[mt][ks]);
        acc[mt][0] = __builtin_amdgcn_mfma_f32_16x16x32_bf16(a, b0, acc[mt][0], 0, 0, 0);
        acc[mt][1] = __builtin_amdgcn_mfma_f32_16x16x32_bf16(a, b1, acc[mt][1], 0, 0, 0);
      }
    }
    if (kb + 1 < 16) {             // cvt + write next tile after MFMAs issued
      WRITE_A(nxt);
      WRITE_B(nxt);
    }
  }
#undef LOAD_B
#undef WRITE_B
#undef LOAD_A
#undef WRITE_A

  // epilogue: D[row=quad*4+r][col=l15] per 16x16 tile
#pragma unroll
  for (int mt = 0; mt < 2; ++mt) {
    const int row0 = gm0 + wm * 32 + mt * 16 + quad * 4;
#pragma unroll
    for (int nt = 0; nt < 2; ++nt) {
      const int colbase = gn0 + wn * 32 + nt * 16;
      const int col = colbase + l15;
      if (colbase < 128) {          // Q (pre-scaled)
#pragma unroll
        for (int r = 0; r < 4; ++r)
          Qb[(size_t)(row0 + r) * H_ + col] = f2bf(acc[mt][nt][r] * CSCALE);
      } else if (colbase < 256) {   // K
#pragma unroll
        for (int r = 0; r < 4; ++r)
          Kb[(size_t)(row0 + r) * H_ + (col - 128)] = f2bf(acc[mt][nt][r]);
      } else {                      // V, transposed
        const int h = col - 256;
        const int bidx = row0 >> 11;
        const int t0 = row0 & 2047;
        ushort4v pk;
        pk[0] = f2bf(acc[mt][nt][0]); pk[1] = f2bf(acc[mt][nt][1]);
        pk[2] = f2bf(acc[mt][nt][2]); pk[3] = f2bf(acc[mt][nt][3]);
        *(ushort4v*)(VT + (size_t)(bidx * H_ + h) * T_ + t0) = pk;
      }
    }
  }
}

// ---------------------------------------------------------------------------
// Kernel 2: flash attention stage 1 (R10, best-known: 115.9us).
// Balanced causal pairing mod-8: block (b,jp,ch in [0,8)) does rows j1=jp,
// j2=31-jp with tiles { t == ch (mod 8), t <= j } -> 4-5 tiles/block.
// T14 reg-staged single-buffer K/V (41 KB LDS), T13 defer-max, T5 setprio,
// shfl-alpha. Occupancy/desync levers falsified (R10 null, R11 regression) —
// structure frozen at best-known.
// ---------------------------------------------------------------------------
__global__ __launch_bounds__(256, 3) void attn1(const unsigned short* __restrict__ Qb,
                                                const unsigned short* __restrict__ Kb,
                                                const unsigned short* __restrict__ VT,
                                                unsigned short* __restrict__ Opart,
                                                float* __restrict__ mpart,
                                                float* __restrict__ lpart) {
  __shared__ unsigned short Ks[64 * 128];      // 16 KB; 16-slot rows
  __shared__ unsigned short Vs[128 * 64];      // 16 KB; 8-slot rows
  __shared__ unsigned short Pls[4][16 * 72];   // 9 KB, per-wave P, pad 72

  const int bid = blockIdx.x;
  const int b  = bid & 3;
  const int jp = (bid >> 2) & 15;
  const int ch = bid >> 6;         // 0..7
  const int j1 = jp, j2 = 31 - jp;
  const int n1 = (ch <= j1) ? (((j1 - ch) >> 3) + 1) : 0;  // tiles for row j1
  const int n2 = ((j2 - ch) >> 3) + 1;                     // tiles for row j2 (>=2)
  const int ntt = n1 + n2;                                 // 4..5 always

  const int tid  = threadIdx.x;
  const int wave = tid >> 6, lane = tid & 63;
  const int quad = lane >> 4, l15 = lane & 15;

  const unsigned short* Kb_b = Kb + (size_t)(b * T_) * H_;
  const unsigned short* VT_b = VT + (size_t)(b * H_) * T_;

  const int k_row4 = lane >> 4, k_slot = lane & 15;
  const int v_row8 = lane >> 3, v_slot = lane & 7;

  // register staging buffers (32 VGPRs)
  f32x4 kreg[4], vreg[4];

  // absolute kv tile index for loop position i_
#define TILE(i_) (((i_) < n1) ? (ch + ((i_) << 3)) : (ch + (((i_) - n1) << 3)))

  // issue global->reg loads for tile at kv0_
#define LOAD_KV(kv0_)                                                              \
  {                                                                                \
    _Pragma("unroll")                                                              \
    for (int i_ = 0; i_ < 4; ++i_) {                                               \
      const int r = wave * 16 + i_ * 4 + k_row4;                                   \
      const int c2 = (k_slot & 8) | ((k_slot ^ r) & 7);                            \
      kreg[i_] = *(const f32x4*)(Kb_b + (size_t)((kv0_) + r) * H_ + c2 * 8);       \
    }                                                                              \
    _Pragma("unroll")                                                              \
    for (int i_ = 0; i_ < 4; ++i_) {                                               \
      const int h = wave * 32 + i_ * 8 + v_row8;                                   \
      vreg[i_] = *(const f32x4*)(VT_b + (size_t)h * T_ + (kv0_) + ((v_slot ^ h) & 7) * 8); \
    }                                                                              \
  }

  // write staged regs -> LDS
#define WRITE_KV()                                                                 \
  {                                                                                \
    _Pragma("unroll")                                                              \
    for (int i_ = 0; i_ < 4; ++i_) {                                               \
      const int r = wave * 16 + i_ * 4 + k_row4;                                   \
      *(f32x4*)(&Ks[r * 128 + k_slot * 8]) = kreg[i_];                             \
    }                                                                              \
    _Pragma("unroll")                                                              \
    for (int i_ = 0; i_ < 4; ++i_) {                                               \
      const int h = wave * 32 + i_ * 8 + v_row8;                                   \
      *(f32x4*)(&Vs[h * 64 + v_slot * 8]) = vreg[i_];                              \
    }                                                                              \
  }

  // partial epilogue: un-normalized O (bf16) + m, l for row jr_
#define EPI(jr_)                                                                   \
  {                                                                                \
    const int pid = (b * 32 + (jr_)) * 8 + ch;                                     \
    unsigned short* po = Opart + (size_t)(pid * 64 + wave * 16) * H_;              \
    _Pragma("unroll")                                                              \
    for (int nth = 0; nth < 8; ++nth)                                              \
      _Pragma("unroll")                                                            \
      for (int r = 0; r < 4; ++r)                                                  \
        po[(quad * 4 + r) * H_ + nth * 16 + l15] = f2bf(O[nth][r]);                \
    if (lane < 16) {                                                               \
      mpart[pid * 64 + wave * 16 + lane] = m_;                                     \
      lpart[pid * 64 + wave * 16 + lane] = l_;                                     \
    }                                                                              \
  }

  // Q fragments for current row block
  int jr_cur = n1 ? j1 : j2;
  short8 aq[4];
  {
    const unsigned short* qrow = Qb + (size_t)(b * T_ + jr_cur * 64 + wave * 16 + l15) * H_;
#pragma unroll
    for (int ks = 0; ks < 4; ++ks)
      aq[ks] = *(const short8*)(qrow + ks * 32 + quad * 8);
  }

  // prologue: stage tile 0, issue loads for tile 1
  LOAD_KV(TILE(0) * 64);
  WRITE_KV();
  LOAD_KV(TILE(1) * 64);   // ntt >= 2 always
  __syncthreads();

  const f32x4 zero4 = {0.f, 0.f, 0.f, 0.f};
  f32x4 O[8];
#pragma unroll
  for (int nth = 0; nth < 8; ++nth) O[nth] = zero4;
  float m_ = NEG_BIG, l_ = 0.f;

  for (int i = 0; i < ntt; ++i) {
    if (n1 && i == n1) {
      // finalize row j1, reset state, switch Q to row j2
      EPI(j1);
      m_ = NEG_BIG; l_ = 0.f;
#pragma unroll
      for (int nth = 0; nth < 8; ++nth) O[nth] = zero4;
      jr_cur = j2;
      const unsigned short* qrow = Qb + (size_t)(b * T_ + j2 * 64 + wave * 16 + l15) * H_;
#pragma unroll
      for (int ks = 0; ks < 4; ++ks)
        aq[ks] = *(const short8*)(qrow + ks * 32 + quad * 8);
    }
    const int ti  = TILE(i);
    const int kv0 = ti * 64;

    // ---- S^T = K . Q^T
    f32x4 ST[4];
    ST[0] = zero4; ST[1] = zero4; ST[2] = zero4; ST[3] = zero4;
    __builtin_amdgcn_s_setprio(1);
#pragma unroll
    for (int ntl = 0; ntl < 4; ++ntl) {
      const int kvr = ntl * 16 + l15;
#pragma unroll
      for (int ks = 0; ks < 4; ++ks) {
        const int c = ks * 4 + quad;
        const int slot = (c & 8) | ((c ^ kvr) & 7);
        short8 kf = *(const short8*)(Ks + kvr * 128 + slot * 8);
        ST[ntl] = __builtin_amdgcn_mfma_f32_16x16x32_bf16(kf, aq[ks], ST[ntl], 0, 0, 0);
      }
    }
    __builtin_amdgcn_s_setprio(0);

    // ---- causal mask (diagonal tile only)
    if (ti == jr_cur) {
      const int ql = jr_cur * 64 + wave * 16 + l15;
#pragma unroll
      for (int ntl = 0; ntl < 4; ++ntl)
#pragma unroll
        for (int r = 0; r < 4; ++r) {
          const int kl = kv0 + ntl * 16 + quad * 4 + r;
          if (kl > ql) ST[ntl][r] = NEG_BIG;
        }
    }

    // ---- softmax (per lane q=l15), defer-max (T13)
    float pmax = ST[0][0];
#pragma unroll
    for (int ntl = 0; ntl < 4; ++ntl)
#pragma unroll
      for (int r = 0; r < 4; ++r) pmax = fmaxf(pmax, ST[ntl][r]);
    pmax = fmaxf(pmax, __shfl_xor(pmax, 16));
    pmax = fmaxf(pmax, __shfl_xor(pmax, 32));
    if (!__all(pmax <= m_ + 8.f)) {
      const float mn = fmaxf(m_, pmax);
      const float alpha = __builtin_amdgcn_exp2f(m_ - mn);
      m_ = mn;
      l_ *= alpha;
      float alr[4];
#pragma unroll
      for (int r = 0; r < 4; ++r) alr[r] = __shfl(alpha, quad * 4 + r);
#pragma unroll
      for (int nth = 0; nth < 8; ++nth)
#pragma unroll
        for (int r = 0; r < 4; ++r) O[nth][r] *= alr[r];
    }
    float s = 0.f;
#pragma unroll
    for (int ntl = 0; ntl < 4; ++ntl)
#pragma unroll
      for (int r = 0; r < 4; ++r) {
        const float p = __builtin_amdgcn_exp2f(ST[ntl][r] - m_);
        ST[ntl][r] = p;
        s += p;
      }
    s += __shfl_xor(s, 16);
    s += __shfl_xor(s, 32);
    l_ += s;

    // ---- P -> LDS ([q][kv] layout; per-wave region, no barrier)
#pragma unroll
    for (int ntl = 0; ntl < 4; ++ntl) {
      ushort4v pk;
      pk[0] = f2bf(ST[ntl][0]); pk[1] = f2bf(ST[ntl][1]);
      pk[2] = f2bf(ST[ntl][2]); pk[3] = f2bf(ST[ntl][3]);
      *(ushort4v*)(&Pls[wave][l15 * 72 + ntl * 16 + quad * 4]) = pk;
    }

    // ---- O += P . V
    short8 ap0 = *(const short8*)(&Pls[wave][l15 * 72 + quad * 8]);
    short8 ap1 = *(const short8*)(&Pls[wave][l15 * 72 + 32 + quad * 8]);
    __builtin_amdgcn_s_setprio(1);
#pragma unroll
    for (int nth = 0; nth < 8; ++nth) {
      const int h = nth * 16 + l15;
      short8 v0 = *(const short8*)(Vs + h * 64 + ((quad ^ h) & 7) * 8);
      short8 v1 = *(const short8*)(Vs + h * 64 + (((4 + quad) ^ h) & 7) * 8);
      O[nth] = __builtin_amdgcn_mfma_f32_16x16x32_bf16(ap0, v0, O[nth], 0, 0, 0);
      O[nth] = __builtin_amdgcn_mfma_f32_16x16x32_bf16(ap1, v1, O[nth], 0, 0, 0);
    }
    __builtin_amdgcn_s_setprio(0);

    // ---- rotate staging: write tile i+1, issue loads for tile i+2
    if (i + 1 < ntt) {
      __syncthreads();             // all waves done reading Ks/Vs (tile i)
      WRITE_KV();                  // stage tile i+1 (regs loaded earlier)
      if (i + 2 < ntt) LOAD_KV(TILE(i + 2) * 64);
      __syncthreads();             // tile i+1 visible
    }
  }
  EPI(j2);
#undef TILE
#undef LOAD_KV
#undef WRITE_KV
#undef EPI
}

// ---------------------------------------------------------------------------
// Kernel 3: stage-2 combine, 512 blocks: b(4) x j(32) x qi(4); each block
// 16 q-rows x 128 h. Row j has contributors ch in [0, min(j+1,8)).
// ---------------------------------------------------------------------------
__global__ __launch_bounds__(256) void attn2(const unsigned short* __restrict__ Opart,
                                             const float* __restrict__ mpart,
                                             const float* __restrict__ lpart,
                                             float* __restrict__ out) {
  const int b = blockIdx.x & 3;
  const int j = (blockIdx.x >> 2) & 31;
  const int qi = blockIdx.x >> 7;     // 0..3
  const int nch = min(j + 1, 8);      // 1..8
  const int tid = threadIdx.x;
  const int q = (tid >> 4) + qi * 16; // 0..63
  const int h0 = (tid & 15) * 8;
  const int pbase = (b * 32 + j) * 8;

  float m_fin = NEG_BIG;
  for (int ch = 0; ch < nch; ++ch)
    m_fin = fmaxf(m_fin, mpart[(pbase + ch) * 64 + q]);
  float lf = 0.f;
  float o[8];
#pragma unroll
  for (int c = 0; c < 8; ++c) o[c] = 0.f;
  for (int ch = 0; ch < nch; ++ch) {
    const int pid = pbase + ch;
    const float sc = __builtin_amdgcn_exp2f(mpart[pid * 64 + q] - m_fin);
    lf += sc * lpart[pid * 64 + q];
    ushort8v pv = *(const ushort8v*)(Opart + (size_t)(pid * 64 + q) * H_ + h0);
#pragma unroll
    for (int c = 0; c < 8; ++c) o[c] += sc * bf2f(pv[c]);
  }
  const float inv = 1.0f / lf;
  float* op = out + (size_t)(b * T_ + j * 64 + q) * H_ + h0;
  f32x4 v0 = {o[0] * inv, o[1] * inv, o[2] * inv, o[3] * inv};
  f32x4 v1 = {o[4] * inv, o[5] * inv, o[6] * inv, o[7] * inv};
  *(f32x4*)(op) = v0;
  *(f32x4*)(op + 4) = v1;
}

// ---------------------------------------------------------------------------
extern "C" void kernel_launch(void* const* d_in, const int* in_sizes, int n_in,
                              void* d_out, int out_size, void* d_ws, size_t ws_size,
                              hipStream_t stream) {
  const float* x  = (const float*)d_in[0];
  const float* Wq = (const float*)d_in[1];
  const float* Wk = (const float*)d_in[2];
  const float* Wv = (const float*)d_in[3];
  float* out = (float*)d_out;

  char* ws = (char*)d_ws;
  unsigned short* Qb  = (unsigned short*)(ws + 1048576);    // [1 MB, 3 MB)
  unsigned short* Kb  = (unsigned short*)(ws + 3145728);    // [3 MB, 5 MB)
  unsigned short* VT  = (unsigned short*)(ws + 5242880);    // [5 MB, 7 MB)
  unsigned short* Opart = (unsigned short*)(ws + 8388608);  // [8 MB, 24 MB)
  float* mpart = (float*)(ws + 25165824);                   // [24 MB, +256 KB)
  float* lpart = (float*)(ws + 25427968);                   // [24.25 MB, +256 KB)

  qkv_proj<<<dim3(768), dim3(256), 0, stream>>>(x, Wq, Wk, Wv, Qb, Kb, VT);
  attn1<<<dim3(512), dim3(256), 0, stream>>>(Qb, Kb, VT, Opart, mpart, lpart);
  attn2<<<dim3(512), dim3(256), 0, stream>>>(Opart, mpart, lpart, out);
}

// Round 13
// 114.693 us; speedup vs baseline: 1.0293x; 1.0049x over previous
//
#include <hip/hip_runtime.h>
#include <stdint.h>

#define B_ 4
#define T_ 2048
#define C_ 1024
#define H_ 128
#define NEG_BIG -3.0e38f

typedef __attribute__((ext_vector_type(8))) short short8;
typedef __attribute__((ext_vector_type(4))) float f32x4;
typedef __attribute__((ext_vector_type(4))) unsigned short ushort4v;
typedef __attribute__((ext_vector_type(8))) unsigned short ushort8v;

// cheap bf16 cast: round-half-up, <=0.5 ULP (validated: absmax unchanged)
__device__ __forceinline__ unsigned short f2bf(float f) {
  union { float f; unsigned u; } cv; cv.f = f;
  return (unsigned short)((cv.u + 0x8000u) >> 16);
}

__device__ __forceinline__ float bf2f(unsigned short s) {
  union { unsigned u; float f; } cv; cv.u = ((unsigned)s) << 16;
  return cv.f;
}

// scale = C^-0.5 = 1/32; folded with log2(e) for exp2-domain softmax
#define CSCALE 0.045084220027780106f

// ---------------------------------------------------------------------------
// Kernel 1: fused weight-cast + x-cast + QKV projection (frozen, best-known).
// 64M x 64N x 64K tiles, grid = 128 rb x 6 cb = 768 blocks -> 3 blocks/CU.
// ---------------------------------------------------------------------------
__global__ __launch_bounds__(256, 3) void qkv_proj(const float* __restrict__ x,
                                                   const float* __restrict__ Wq,
                                                   const float* __restrict__ Wk,
                                                   const float* __restrict__ Wv,
                                                   unsigned short* __restrict__ Qb,
                                                   unsigned short* __restrict__ Kb,
                                                   unsigned short* __restrict__ VT) {
  __shared__ unsigned short As[2][64 * 64];   // 8 KB each
  __shared__ unsigned short Bs[2][64 * 64];   // 8 KB each

  const int tid  = threadIdx.x;
  const int wave = tid >> 6, lane = tid & 63;
  const int quad = lane >> 4, l15 = lane & 15;
  const int rb = blockIdx.x & 127, cb = blockIdx.x >> 7;  // siblings same XCD
  const int gm0 = rb * 64, gn0 = cb * 64;
  const int wm = wave >> 1, wn = wave & 1;

  // B staging: thread -> (row bn = tid&63, k-chunk16 bkc = tid>>6)
  const int bn = tid & 63, bkc = tid >> 6;
  const float* Wsrc = (cb < 2) ? Wq : (cb < 4) ? Wk : Wv;
  const int bh = (gn0 & 127) + bn;            // column within Wsrc

  // A staging: thread -> (row = tid>>3 (+32q), chunk = tid&7)
  const int axr = tid >> 3, axc = tid & 7;    // 32 rows x 8 chunks
  const float* gAx = x + (size_t)(gm0 + axr) * C_ + axc * 8;

  // fragment read offsets (shorts)
  int aoff[2][2], boff[2][2];
#pragma unroll
  for (int mt = 0; mt < 2; ++mt) {
    const int r = wm * 32 + mt * 16 + l15;
#pragma unroll
    for (int ks = 0; ks < 2; ++ks)
      aoff[mt][ks] = r * 64 + (((ks * 4 + quad) ^ r) & 7) * 8;
  }
#pragma unroll
  for (int nt = 0; nt < 2; ++nt) {
    const int r = wn * 32 + nt * 16 + l15;
#pragma unroll
    for (int ks = 0; ks < 2; ++ks)
      boff[nt][ks] = r * 64 + ((((ks * 4 + quad)) ^ r ^ (r >> 3)) & 7) * 8;
  }

  f32x4 acc[2][2];
  const f32x4 zero4 = {0.f, 0.f, 0.f, 0.f};
#pragma unroll
  for (int mt = 0; mt < 2; ++mt)
#pragma unroll
    for (int nt = 0; nt < 2; ++nt) acc[mt][nt] = zero4;

#define LOAD_B(ko_)                                                                \
  _Pragma("unroll")                                                                \
  for (int kk = 0; kk < 16; ++kk)                                                  \
    bv[kk] = Wsrc[(size_t)((ko_) + bkc * 16 + kk) * 128 + bh];

#define WRITE_B(buf)                                                               \
  {                                                                                \
    short8 bw0, bw1;                                                               \
    _Pragma("unroll")                                                              \
    for (int e = 0; e < 8; ++e) {                                                  \
      bw0[e] = (short)f2bf(bv[e]);                                                 \
      bw1[e] = (short)f2bf(bv[8 + e]);                                             \
    }                                                                              \
    const int sx = bn ^ (bn >> 3);                                                 \
    *(short8*)(&Bs[buf][bn * 64 + (((bkc * 2) ^ sx) & 7) * 8]) = bw0;              \
    *(short8*)(&Bs[buf][bn * 64 + (((bkc * 2 + 1) ^ sx) & 7) * 8]) = bw1;          \
  }

#define LOAD_A(ko_)                                                                \
  _Pragma("unroll")                                                                \
  for (int q = 0; q < 2; ++q) {                                                    \
    av0[q] = *(const f32x4*)(gAx + (size_t)(q * 32) * C_ + (ko_));                 \
    av1[q] = *(const f32x4*)(gAx + (size_t)(q * 32) * C_ + (ko_) + 4);             \
  }

#define WRITE_A(buf)                                                               \
  _Pragma("unroll")                                                                \
  for (int q = 0; q < 2; ++q) {                                                    \
    const int row = axr + q * 32;                                                  \
    short8 aw;                                                                     \
    _Pragma("unroll")                                                              \
    for (int e = 0; e < 4; ++e) {                                                  \
      aw[e]     = (short)f2bf(av0[q][e]);                                          \
      aw[4 + e] = (short)f2bf(av1[q][e]);                                          \
    }                                                                              \
    *(short8*)(&As[buf][row * 64 + ((axc ^ row) & 7) * 8]) = aw;                   \
  }

  f32x4 av0[2], av1[2];
  float bv[16];
  LOAD_A(0);
  LOAD_B(0);
  WRITE_A(0);
  WRITE_B(0);

  for (int kb = 0; kb < 16; ++kb) {
    __syncthreads();               // buf[kb&1] staged; prior reads of other done
    const int cur = kb & 1, nxt = cur ^ 1;
    if (kb + 1 < 16) {             // issue next-tile loads right after barrier
      LOAD_A((kb + 1) * 64);
      LOAD_B((kb + 1) * 64);
    }
    const unsigned short* Ac = As[cur];
    const unsigned short* Bc = Bs[cur];
#pragma unroll
    for (int ks = 0; ks < 2; ++ks) {
      short8 b0 = *(const short8*)(Bc + boff[0][ks]);
      short8 b1 = *(const short8*)(Bc + boff[1][ks]);
#pragma unroll
      for (int mt = 0; mt < 2; ++mt) {
        short8 a = *(const short8*)(Ac + aoff[mt][ks]);
        acc[mt][0] = __builtin_amdgcn_mfma_f32_16x16x32_bf16(a, b0, acc[mt][0], 0, 0, 0);
        acc[mt][1] = __builtin_amdgcn_mfma_f32_16x16x32_bf16(a, b1, acc[mt][1], 0, 0, 0);
      }
    }
    if (kb + 1 < 16) {             // cvt + write next tile after MFMAs issued
      WRITE_A(nxt);
      WRITE_B(nxt);
    }
  }
#undef LOAD_B
#undef WRITE_B
#undef LOAD_A
#undef WRITE_A

  // epilogue: D[row=quad*4+r][col=l15] per 16x16 tile
#pragma unroll
  for (int mt = 0; mt < 2; ++mt) {
    const int row0 = gm0 + wm * 32 + mt * 16 + quad * 4;
#pragma unroll
    for (int nt = 0; nt < 2; ++nt) {
      const int colbase = gn0 + wn * 32 + nt * 16;
      const int col = colbase + l15;
      if (colbase < 128) {          // Q (pre-scaled)
#pragma unroll
        for (int r = 0; r < 4; ++r)
          Qb[(size_t)(row0 + r) * H_ + col] = f2bf(acc[mt][nt][r] * CSCALE);
      } else if (colbase < 256) {   // K
#pragma unroll
        for (int r = 0; r < 4; ++r)
          Kb[(size_t)(row0 + r) * H_ + (col - 128)] = f2bf(acc[mt][nt][r]);
      } else {                      // V, transposed
        const int h = col - 256;
        const int bidx = row0 >> 11;
        const int t0 = row0 & 2047;
        ushort4v pk;
        pk[0] = f2bf(acc[mt][nt][0]); pk[1] = f2bf(acc[mt][nt][1]);
        pk[2] = f2bf(acc[mt][nt][2]); pk[3] = f2bf(acc[mt][nt][3]);
        *(ushort4v*)(VT + (size_t)(bidx * H_ + h) * T_ + t0) = pk;
      }
    }
  }
}

// ---------------------------------------------------------------------------
// Kernel 2: flash attention stage 1.
// R13: SINGLE-PASS DUAL-ROW — tiles(j1) is a subset of tiles(j2) (both start
// at tile ch, stride 8, j1 <= j2), so iterate the tile stream ONCE (n2 iters)
// and per tile run QK->softmax->PV for j1 (while i < n1) then j2, holding
// both rows' states in registers. Eliminates the 26% duplicate K/V stagings
// (Sum n1 = 544 of 2112) and cuts the worst block's serial stage slots 5->3.
// Per-row tile order and arithmetic are bit-identical -> absmax unchanged.
// T14 reg-staged single-buffer K/V, T13 defer-max, T5 setprio, shfl-alpha.
// launch_bounds(256,2): grid 512 = 2/CU regardless; extra ~80 VGPRs OK.
// ---------------------------------------------------------------------------
__global__ __launch_bounds__(256, 2) void attn1(const unsigned short* __restrict__ Qb,
                                                const unsigned short* __restrict__ Kb,
                                                const unsigned short* __restrict__ VT,
                                                unsigned short* __restrict__ Opart,
                                                float* __restrict__ mpart,
                                                float* __restrict__ lpart) {
  __shared__ unsigned short Ks[64 * 128];      // 16 KB; 16-slot rows
  __shared__ unsigned short Vs[128 * 64];      // 16 KB; 8-slot rows
  __shared__ unsigned short Pls[4][16 * 72];   // 9 KB, per-wave P, pad 72

  const int bid = blockIdx.x;
  const int b  = bid & 3;
  const int jp = (bid >> 2) & 15;
  const int ch = bid >> 6;         // 0..7
  const int j1 = jp, j2 = 31 - jp;
  const int n1 = (ch <= j1) ? (((j1 - ch) >> 3) + 1) : 0;  // tiles for row j1 (0..2)
  const int n2 = ((j2 - ch) >> 3) + 1;                     // tiles for row j2 (>=2)

  const int tid  = threadIdx.x;
  const int wave = tid >> 6, lane = tid & 63;
  const int quad = lane >> 4, l15 = lane & 15;

  const unsigned short* Kb_b = Kb + (size_t)(b * T_) * H_;
  const unsigned short* VT_b = VT + (size_t)(b * H_) * T_;

  const int k_row4 = lane >> 4, k_slot = lane & 15;
  const int v_row8 = lane >> 3, v_slot = lane & 7;

  // register staging buffers (32 VGPRs)
  f32x4 kreg[4], vreg[4];

  // issue global->reg loads for tile at kv0_
#define LOAD_KV(kv0_)                                                              \
  {                                                                                \
    _Pragma("unroll")                                                              \
    for (int i_ = 0; i_ < 4; ++i_) {                                               \
      const int r = wave * 16 + i_ * 4 + k_row4;                                   \
      const int c2 = (k_slot & 8) | ((k_slot ^ r) & 7);                            \
      kreg[i_] = *(const f32x4*)(Kb_b + (size_t)((kv0_) + r) * H_ + c2 * 8);       \
    }                                                                              \
    _Pragma("unroll")                                                              \
    for (int i_ = 0; i_ < 4; ++i_) {                                               \
      const int h = wave * 32 + i_ * 8 + v_row8;                                   \
      vreg[i_] = *(const f32x4*)(VT_b + (size_t)h * T_ + (kv0_) + ((v_slot ^ h) & 7) * 8); \
    }                                                                              \
  }

  // write staged regs -> LDS
#define WRITE_KV()                                                                 \
  {                                                                                \
    _Pragma("unroll")                                                              \
    for (int i_ = 0; i_ < 4; ++i_) {                                               \
      const int r = wave * 16 + i_ * 4 + k_row4;                                   \
      *(f32x4*)(&Ks[r * 128 + k_slot * 8]) = kreg[i_];                             \
    }                                                                              \
    _Pragma("unroll")                                                              \
    for (int i_ = 0; i_ < 4; ++i_) {                                               \
      const int h = wave * 32 + i_ * 8 + v_row8;                                   \
      *(f32x4*)(&Vs[h * 64 + v_slot * 8]) = vreg[i_];                              \
    }                                                                              \
  }

  // full per-tile row update: QK^T -> mask -> defer-max softmax -> P-LDS -> PV
#define PROCESS(jr_, aq_, O_, mv_, lv_)                                            \
  {                                                                                \
    f32x4 ST[4];                                                                   \
    ST[0] = zero4; ST[1] = zero4; ST[2] = zero4; ST[3] = zero4;                    \
    __builtin_amdgcn_s_setprio(1);                                                 \
    _Pragma("unroll")                                                              \
    for (int ntl = 0; ntl < 4; ++ntl) {                                            \
      const int kvr = ntl * 16 + l15;                                              \
      _Pragma("unroll")                                                            \
      for (int ks = 0; ks < 4; ++ks) {                                             \
        const int c = ks * 4 + quad;                                               \
        const int slot = (c & 8) | ((c ^ kvr) & 7);                                \
        short8 kf = *(const short8*)(Ks + kvr * 128 + slot * 8);                   \
        ST[ntl] = __builtin_amdgcn_mfma_f32_16x16x32_bf16(kf, aq_[ks], ST[ntl], 0, 0, 0); \
      }                                                                            \
    }                                                                              \
    __builtin_amdgcn_s_setprio(0);                                                 \
    if (ti == (jr_)) {                                                             \
      const int ql = (jr_) * 64 + wave * 16 + l15;                                 \
      _Pragma("unroll")                                                            \
      for (int ntl = 0; ntl < 4; ++ntl)                                            \
        _Pragma("unroll")                                                          \
        for (int r = 0; r < 4; ++r) {                                              \
          const int kl = kv0 + ntl * 16 + quad * 4 + r;                            \
          if (kl > ql) ST[ntl][r] = NEG_BIG;                                       \
        }                                                                          \
    }                                                                              \
    float pmax = ST[0][0];                                                         \
    _Pragma("unroll")                                                              \
    for (int ntl = 0; ntl < 4; ++ntl)                                              \
      _Pragma("unroll")                                                            \
      for (int r = 0; r < 4; ++r) pmax = fmaxf(pmax, ST[ntl][r]);                  \
    pmax = fmaxf(pmax, __shfl_xor(pmax, 16));                                      \
    pmax = fmaxf(pmax, __shfl_xor(pmax, 32));                                      \
    if (!__all(pmax <= (mv_) + 8.f)) {                                             \
      const float mn = fmaxf((mv_), pmax);                                         \
      const float alpha = __builtin_amdgcn_exp2f((mv_) - mn);                      \
      (mv_) = mn;                                                                  \
      (lv_) *= alpha;                                                              \
      float alr[4];                                                                \
      _Pragma("unroll")                                                            \
      for (int r = 0; r < 4; ++r) alr[r] = __shfl(alpha, quad * 4 + r);            \
      _Pragma("unroll")                                                            \
      for (int nth = 0; nth < 8; ++nth)                                            \
        _Pragma("unroll")                                                          \
        for (int r = 0; r < 4; ++r) O_[nth][r] *= alr[r];                          \
    }                                                                              \
    float s = 0.f;                                                                 \
    _Pragma("unroll")                                                              \
    for (int ntl = 0; ntl < 4; ++ntl)                                              \
      _Pragma("unroll")                                                            \
      for (int r = 0; r < 4; ++r) {                                                \
        const float p = __builtin_amdgcn_exp2f(ST[ntl][r] - (mv_));                \
        ST[ntl][r] = p;                                                            \
        s += p;                                                                    \
      }                                                                            \
    s += __shfl_xor(s, 16);                                                        \
    s += __shfl_xor(s, 32);                                                        \
    (lv_) += s;                                                                    \
    _Pragma("unroll")                                                              \
    for (int ntl = 0; ntl < 4; ++ntl) {                                            \
      ushort4v pk;                                                                 \
      pk[0] = f2bf(ST[ntl][0]); pk[1] = f2bf(ST[ntl][1]);                          \
      pk[2] = f2bf(ST[ntl][2]); pk[3] = f2bf(ST[ntl][3]);                          \
      *(ushort4v*)(&Pls[wave][l15 * 72 + ntl * 16 + quad * 4]) = pk;               \
    }                                                                              \
    short8 ap0 = *(const short8*)(&Pls[wave][l15 * 72 + quad * 8]);                \
    short8 ap1 = *(const short8*)(&Pls[wave][l15 * 72 + 32 + quad * 8]);           \
    __builtin_amdgcn_s_setprio(1);                                                 \
    _Pragma("unroll")                                                              \
    for (int nth = 0; nth < 8; ++nth) {                                            \
      const int h = nth * 16 + l15;                                                \
      short8 v0 = *(const short8*)(Vs + h * 64 + ((quad ^ h) & 7) * 8);            \
      short8 v1 = *(const short8*)(Vs + h * 64 + (((4 + quad) ^ h) & 7) * 8);      \
      O_[nth] = __builtin_amdgcn_mfma_f32_16x16x32_bf16(ap0, v0, O_[nth], 0, 0, 0); \
      O_[nth] = __builtin_amdgcn_mfma_f32_16x16x32_bf16(ap1, v1, O_[nth], 0, 0, 0); \
    }                                                                              \
    __builtin_amdgcn_s_setprio(0);                                                 \
  }

  // partial epilogue: un-normalized O (bf16) + m, l for row jr_
#define EPI(jr_, O_, mv_, lv_)                                                     \
  {                                                                                \
    const int pid = (b * 32 + (jr_)) * 8 + ch;                                     \
    unsigned short* po = Opart + (size_t)(pid * 64 + wave * 16) * H_;              \
    _Pragma("unroll")                                                              \
    for (int nth = 0; nth < 8; ++nth)                                              \
      _Pragma("unroll")                                                            \
      for (int r = 0; r < 4; ++r)                                                  \
        po[(quad * 4 + r) * H_ + nth * 16 + l15] = f2bf(O_[nth][r]);               \
    if (lane < 16) {                                                               \
      mpart[pid * 64 + wave * 16 + lane] = (mv_);                                  \
      lpart[pid * 64 + wave * 16 + lane] = (lv_);                                  \
    }                                                                              \
  }

  // Q fragments for both rows (j1 only when n1 > 0)
  short8 aq1[4], aq2[4];
  {
    const unsigned short* q2row = Qb + (size_t)(b * T_ + j2 * 64 + wave * 16 + l15) * H_;
#pragma unroll
    for (int ks = 0; ks < 4; ++ks)
      aq2[ks] = *(const short8*)(q2row + ks * 32 + quad * 8);
  }
  if (n1) {
    const unsigned short* q1row = Qb + (size_t)(b * T_ + j1 * 64 + wave * 16 + l15) * H_;
#pragma unroll
    for (int ks = 0; ks < 4; ++ks)
      aq1[ks] = *(const short8*)(q1row + ks * 32 + quad * 8);
  }

  // prologue: stage tile ch, issue loads for tile ch+8
  LOAD_KV(ch * 64);
  WRITE_KV();
  if (n2 > 1) LOAD_KV((ch + 8) * 64);
  __syncthreads();

  const f32x4 zero4 = {0.f, 0.f, 0.f, 0.f};
  f32x4 O1[8], O2[8];
#pragma unroll
  for (int nth = 0; nth < 8; ++nth) { O1[nth] = zero4; O2[nth] = zero4; }
  float m1 = NEG_BIG, l1 = 0.f, m2 = NEG_BIG, l2 = 0.f;

  for (int i = 0; i < n2; ++i) {
    const int ti  = ch + (i << 3);
    const int kv0 = ti * 64;

    if (i < n1) PROCESS(j1, aq1, O1, m1, l1);
    PROCESS(j2, aq2, O2, m2, l2);

    // rotate staging: write tile i+1, issue loads for tile i+2
    if (i + 1 < n2) {
      __syncthreads();             // all waves done reading Ks/Vs (tile i)
      WRITE_KV();                  // stage tile i+1 (regs loaded earlier)
      if (i + 2 < n2) LOAD_KV((ch + ((i + 2) << 3)) * 64);
      __syncthreads();             // tile i+1 visible
    }
  }
  if (n1) EPI(j1, O1, m1, l1);
  EPI(j2, O2, m2, l2);
#undef LOAD_KV
#undef WRITE_KV
#undef PROCESS
#undef EPI
}

// ---------------------------------------------------------------------------
// Kernel 3: stage-2 combine, 512 blocks: b(4) x j(32) x qi(4); each block
// 16 q-rows x 128 h. Row j has contributors ch in [0, min(j+1,8)).
// ---------------------------------------------------------------------------
__global__ __launch_bounds__(256) void attn2(const unsigned short* __restrict__ Opart,
                                             const float* __restrict__ mpart,
                                             const float* __restrict__ lpart,
                                             float* __restrict__ out) {
  const int b = blockIdx.x & 3;
  const int j = (blockIdx.x >> 2) & 31;
  const int qi = blockIdx.x >> 7;     // 0..3
  const int nch = min(j + 1, 8);      // 1..8
  const int tid = threadIdx.x;
  const int q = (tid >> 4) + qi * 16; // 0..63
  const int h0 = (tid & 15) * 8;
  const int pbase = (b * 32 + j) * 8;

  float m_fin = NEG_BIG;
  for (int ch = 0; ch < nch; ++ch)
    m_fin = fmaxf(m_fin, mpart[(pbase + ch) * 64 + q]);
  float lf = 0.f;
  float o[8];
#pragma unroll
  for (int c = 0; c < 8; ++c) o[c] = 0.f;
  for (int ch = 0; ch < nch; ++ch) {
    const int pid = pbase + ch;
    const float sc = __builtin_amdgcn_exp2f(mpart[pid * 64 + q] - m_fin);
    lf += sc * lpart[pid * 64 + q];
    ushort8v pv = *(const ushort8v*)(Opart + (size_t)(pid * 64 + q) * H_ + h0);
#pragma unroll
    for (int c = 0; c < 8; ++c) o[c] += sc * bf2f(pv[c]);
  }
  const float inv = 1.0f / lf;
  float* op = out + (size_t)(b * T_ + j * 64 + q) * H_ + h0;
  f32x4 v0 = {o[0] * inv, o[1] * inv, o[2] * inv, o[3] * inv};
  f32x4 v1 = {o[4] * inv, o[5] * inv, o[6] * inv, o[7] * inv};
  *(f32x4*)(op) = v0;
  *(f32x4*)(op + 4) = v1;
}

// ---------------------------------------------------------------------------
extern "C" void kernel_launch(void* const* d_in, const int* in_sizes, int n_in,
                              void* d_out, int out_size, void* d_ws, size_t ws_size,
                              hipStream_t stream) {
  const float* x  = (const float*)d_in[0];
  const float* Wq = (const float*)d_in[1];
  const float* Wk = (const float*)d_in[2];
  const float* Wv = (const float*)d_in[3];
  float* out = (float*)d_out;

  char* ws = (char*)d_ws;
  unsigned short* Qb  = (unsigned short*)(ws + 1048576);    // [1 MB, 3 MB)
  unsigned short* Kb  = (unsigned short*)(ws + 3145728);    // [3 MB, 5 MB)
  unsigned short* VT  = (unsigned short*)(ws + 5242880);    // [5 MB, 7 MB)
  unsigned short* Opart = (unsigned short*)(ws + 8388608);  // [8 MB, 24 MB)
  float* mpart = (float*)(ws + 25165824);                   // [24 MB, +256 KB)
  float* lpart = (float*)(ws + 25427968);                   // [24.25 MB, +256 KB)

  qkv_proj<<<dim3(768), dim3(256), 0, stream>>>(x, Wq, Wk, Wv, Qb, Kb, VT);
  attn1<<<dim3(512), dim3(256), 0, stream>>>(Qb, Kb, VT, Opart, mpart, lpart);
  attn2<<<dim3(512), dim3(256), 0, stream>>>(Opart, mpart, lpart, out);
}